// Round 9
// baseline (125.937 us; speedup 1.0000x reference)
//
#include <hip/hip_runtime.h>
#include <hip/hip_bf16.h>

// CompletePatchReadout: grouped GEMM (128 patches, M=32 K=1536 N=768) + bias + scatter.
// Round-9 = R8 + 2-deep register W pipeline + raw s_barrier (no vmcnt(0) drain).
// R8's loop consumed tile s+1's loads in the same step it issued them -> writeW stalled
// on the delivery tail, then writeW+barrier ran with zero loads in flight (CU memory
// pipe idle ~15%/step; 1 block/CU = no TLP cover). Now tiles are issued 2 steps ahead
// into named reg buffers (wsA/wsB, unroll-2 for static indexing), and __syncthreads is
// replaced by lgkmcnt(0)+s_barrier (8-phase-template pattern) so prefetch stays in
// flight across barriers. Cross-wave comms is LDS-only -> lgkmcnt(0) suffices.

constexpr int T      = 12;
constexpr int P      = 128;
constexpr int F      = 128;
constexpr int K      = T * F;        // 1536
constexpr int N      = 768;
constexpr int NPP    = 64;
constexpr int H      = 12;
constexpr int NNODES = P * NPP;      // 8192
constexpr int BN     = 384;          // N-half per block
constexpr int NSTEP  = 48;           // K32 steps
constexpr int TPF    = T * P * F;
constexpr int PF     = P * F;

typedef __attribute__((ext_vector_type(8))) short        bf16x8;
typedef __attribute__((ext_vector_type(4))) float        f32x4;
typedef __attribute__((ext_vector_type(4))) unsigned int u32x4;

__device__ inline unsigned short f2bfu(float f) {
    return __bfloat16_as_ushort(__float2bfloat16(f));
}
__device__ inline unsigned int pk2(float lo, float hi) {
    return (unsigned int)f2bfu(lo) | ((unsigned int)f2bfu(hi) << 16);
}

__global__ __launch_bounds__(384, 1)
void patch_readout_kernel(const float* __restrict__ x,
                          const float* __restrict__ W,
                          const float* __restrict__ bias,
                          const int*   __restrict__ map,
                          float*       __restrict__ out)
{
    __shared__ short Xs[32 * K];          // 96 KB: whole x-panel, bf16, swizzled
    __shared__ short Ws2[2][4 * BN * 8];  // 2 x 24 KB: W K32-tile, [octet][col][8 bf16]
    char* xl  = (char*)&Xs[0];
    char* wlb = (char*)&Ws2[0][0];

    // XCD swizzle: 256 blocks = 8 XCDs x 32; patch-pair (2 blocks) lands on one XCD.
    const int bid = blockIdx.x;
    const int lgc = (bid & 7) * 32 + (bid >> 3);
    const int p   = lgc >> 1;
    const int n0  = (lgc & 1) * BN;

    const int tid  = threadIdx.x;         // 0..383 (6 waves)
    const int lane = tid & 63;
    const int wv   = tid >> 6;            // wave -> 64-col slice
    const int r    = lane & 15;
    const int c    = lane >> 4;           // k-octet 0..3 within K32

    // --- W loaders: thread (c2,q) owns k-octet c2, cols 4q..4q+3 (dense dwordx4) ---
    const int c2 = tid / 96;              // 0..3
    const int q  = tid - c2 * 96;         // 0..95
    const float* wg = W + (size_t)p * K * N + (size_t)(8 * c2) * N + (n0 + 4 * q);

    f32x4 wsA[8], wsB[8];                 // 2-deep prefetch (NAMED buffers, rule #20)

    auto issueInto = [&](int t, f32x4* b) {
        #pragma unroll
        for (int j = 0; j < 8; ++j)
            b[j] = *(const f32x4*)(wg + (size_t)(t * 32 + j) * N);
    };

    auto writeFrom = [&](int d, const f32x4* b) {  // pack + transposed swizzled store
        char* wl = wlb + d * 24576 + c2 * 6144;
        #pragma unroll
        for (int i = 0; i < 4; ++i) {
            u32x4 wd;
            wd.x = pk2(b[0][i], b[1][i]);
            wd.y = pk2(b[2][i], b[3][i]);
            wd.z = pk2(b[4][i], b[5][i]);
            wd.w = pk2(b[6][i], b[7][i]);
            const int col = 4 * q + i;
            *(u32x4*)(wl + ((col * 16) ^ (((col >> 3) & 7) << 4))) = wd;
        }
    };

    auto stageX = [&]() {                 // whole panel, once: 32 rows x 1536 k
        const int row = tid / 12;         // 384 = 32 x 12 exact
        const int sub = tid - row * 12;   // t-chunk
        const float* xg = x + (size_t)row * TPF + (size_t)sub * PF + (size_t)p * F;
        char* xw = xl + row * 3072;
        const int sw = (row & 7) << 4;
        #pragma unroll
        for (int ci = 0; ci < 16; ++ci) {
            f32x4 v0 = *(const f32x4*)(xg + ci * 8);
            f32x4 v1 = *(const f32x4*)(xg + ci * 8 + 4);
            bf16x8 xv;
            xv[0] = (short)f2bfu(v0.x); xv[1] = (short)f2bfu(v0.y);
            xv[2] = (short)f2bfu(v0.z); xv[3] = (short)f2bfu(v0.w);
            xv[4] = (short)f2bfu(v1.x); xv[5] = (short)f2bfu(v1.y);
            xv[6] = (short)f2bfu(v1.z); xv[7] = (short)f2bfu(v1.w);
            *(bf16x8*)(xw + ((sub * 256 + ci * 16) ^ sw)) = xv;
        }
    };

    f32x4 acc[2][4] = {};                 // [mi][ni]

    auto compute = [&](int s, int d) {
        const char* wl = wlb + d * 24576 + c * 6144;
        bf16x8 af[2];
        #pragma unroll
        for (int mi = 0; mi < 2; ++mi) {
            const int row = mi * 16 + r;
            af[mi] = *(const bf16x8*)(xl + row * 3072 +
                                      ((s * 64 + c * 16) ^ ((row & 7) << 4)));
        }
        #pragma unroll
        for (int ni = 0; ni < 4; ++ni) {
            const int col = wv * 64 + ni * 16 + r;
            bf16x8 bf = *(const bf16x8*)(wl + ((col * 16) ^ (((col >> 3) & 7) << 4)));
            #pragma unroll
            for (int mi = 0; mi < 2; ++mi)
                acc[mi][ni] = __builtin_amdgcn_mfma_f32_16x16x32_bf16(
                    af[mi], bf, acc[mi][ni], 0, 0, 0);
        }
    };

    #define LBAR() do { asm volatile("s_waitcnt lgkmcnt(0)" ::: "memory"); \
                        __builtin_amdgcn_s_barrier(); } while (0)

    // prologue: tiles 0,1 in flight; x stages under tile-0's latency
    issueInto(0, wsA);
    stageX();
    issueInto(1, wsB);
    writeFrom(0, wsA);                    // counted vmcnt: tile-1 loads stay in flight
    LBAR();

    // steady state: tile t lives in reg buf (t&1 ? wsB : wsA) and LDS buf t&1.
    for (int ss = 0; ss < 24; ++ss) {
        const int s0 = ss * 2;            // even step, LDS buf 0
        if (s0 < 46) issueInto(s0 + 2, wsA);
        compute(s0, 0);
        writeFrom(1, wsB);                // tile s0+1; waits its loads (1 step old)
        LBAR();

        const int s1 = s0 + 1;            // odd step, LDS buf 1
        if (s1 < 46) issueInto(s1 + 2, wsB);
        compute(s1, 1);
        if (s1 < 47) writeFrom(0, wsA);   // tile s1+1
        LBAR();
    }
    #undef LBAR

    // ---- epilogue: bias + permutation scatter (verified layout) ----
    #pragma unroll
    for (int ni = 0; ni < 4; ++ni) {
        const int col = n0 + wv * 64 + ni * 16 + r;
        const int nl  = col / H;
        const int h   = col - nl * H;
        const int g   = map[p * NPP + nl];
        const float bv = bias[p * N + col];
        #pragma unroll
        for (int mi = 0; mi < 2; ++mi) {
            #pragma unroll
            for (int i = 0; i < 4; ++i) {
                const int b = mi * 16 + c * 4 + i;
                out[((size_t)b * NNODES + g) * H + h] = acc[mi][ni][i] + bv;
            }
        }
    }
}

extern "C" void kernel_launch(void* const* d_in, const int* in_sizes, int n_in,
                              void* d_out, int out_size, void* d_ws, size_t ws_size,
                              hipStream_t stream) {
    const float* x    = (const float*)d_in[0];
    const float* W    = (const float*)d_in[1];
    const float* bias = (const float*)d_in[2];
    const int*   map  = (const int*)d_in[3];
    float*       out  = (float*)d_out;

    dim3 grid(256);     // 1 block per CU exactly
    dim3 block(384);
    patch_readout_kernel<<<grid, block, 0, stream>>>(x, W, bias, map, out);
}